// Round 3
// baseline (459.427 us; speedup 1.0000x reference)
//
#include <hip/hip_runtime.h>
#include <stdint.h>

// ---------- types ----------
using s8v  = __attribute__((ext_vector_type(8))) short;    // 8 bf16 (A/B frag)
using f4   = __attribute__((ext_vector_type(4))) float;    // C/D frag
using u32x4 = __attribute__((ext_vector_type(4))) uint32_t;
using u32x2 = __attribute__((ext_vector_type(2))) uint32_t;
using vf4  = __attribute__((ext_vector_type(4))) float;
using i4v  = __attribute__((ext_vector_type(4))) int;

typedef unsigned short ushortT;

// bf16 round-to-nearest-even
static __device__ __forceinline__ uint32_t bfr16(float f) {
  union { float f; uint32_t u; } v; v.f = f;
  return (v.u + 0x7FFFu + ((v.u >> 16) & 1u)) >> 16;
}
static __device__ __forceinline__ uint32_t pk2(float lo, float hi) {
  return (bfr16(hi) << 16) | (bfr16(lo) & 0xFFFFu);
}
// hardware packed f32x2 -> bf16x2 (RNE)
static __device__ __forceinline__ uint32_t cvtpk(float lo, float hi) {
  uint32_t r;
  asm("v_cvt_pk_bf16_f32 %0, %1, %2" : "=v"(r) : "v"(lo), "v"(hi));
  return r;
}
// async global->LDS, 16B per lane (kproj only)
static __device__ __forceinline__ void gl16(const void* g, void* l) {
  __builtin_amdgcn_global_load_lds((const __attribute__((address_space(1))) uint32_t*)g,
                                   (__attribute__((address_space(3))) uint32_t*)l, 16, 0, 0);
}

#define MFMA_BF16(A, B, C) __builtin_amdgcn_mfma_f32_16x16x32_bf16((A), (B), (C), 0, 0, 0)

// ---------------------------------------------------------------------------
// Kernel 0: weights -> bf16, transposed: Wt[640][512]
// ---------------------------------------------------------------------------
__global__ __launch_bounds__(64) void kprep(const float* __restrict__ Wg,
                                            const float* __restrict__ Wf,
                                            const float* __restrict__ Wh,
                                            ushortT* __restrict__ Wt) {
  const int cIdx = blockIdx.x;     // 0..639
  const int t = threadIdx.x;       // 64
  const float* src; int co, ldc;
  if (cIdx < 64)       { src = Wg; co = cIdx;       ldc = 64;  }
  else if (cIdx < 128) { src = Wf; co = cIdx - 64;  ldc = 64;  }
  else                 { src = Wh; co = cIdx - 128; ldc = 512; }
#pragma unroll
  for (int kk = 0; kk < 8; ++kk) {
    int k = kk * 64 + t;
    Wt[(size_t)cIdx * 512 + k] = (ushortT)bfr16(src[(size_t)k * ldc + co]);
  }
}

// ---------------------------------------------------------------------------
// Kernel 1: projection GEMM.  col-tile 0 -> Q [32768][64]; 1 -> K [32768][64];
// 2..9 -> Vt2 TILED: Vt2[b][kvtile=128][col=512][kv=32]  (so kattn's per-wave
// V fragments are one base + {0,1,2,3}KB imm offsets).
// ---------------------------------------------------------------------------
__global__ __launch_bounds__(256) void kproj(const float* __restrict__ x,
                                             const ushortT* __restrict__ Wt,
                                             const float* __restrict__ bg,
                                             const float* __restrict__ bfv,
                                             const float* __restrict__ bh,
                                             ushortT* __restrict__ Q,
                                             ushortT* __restrict__ K,
                                             ushortT* __restrict__ Vt) {
  __shared__ ushortT Al[64 * 64];
  __shared__ ushortT Bl[64 * 64];

  const int tid = threadIdx.x;
  const int w = tid >> 6, l = tid & 63, h = l >> 4, c = l & 15;
  const int ct = blockIdx.x, rt = blockIdx.y;
  const int row0 = rt * 64;

  f4 acc[4];
#pragma unroll
  for (int j = 0; j < 4; ++j) acc[j] = (f4){0.f, 0.f, 0.f, 0.f};

  const int arow = tid >> 2, aseg = tid & 3;
  const float* xrow = x + (size_t)(row0 + arow) * 512 + aseg * 16;

  for (int kk = 0; kk < 8; ++kk) {
    const int k0 = kk * 64;
    vf4 f0 = *(const vf4*)(xrow + k0 + 0);
    vf4 f1 = *(const vf4*)(xrow + k0 + 4);
    vf4 f2 = *(const vf4*)(xrow + k0 + 8);
    vf4 f3 = *(const vf4*)(xrow + k0 + 12);
    u32x4 ch0 = { pk2(f0[0], f0[1]), pk2(f0[2], f0[3]), pk2(f1[0], f1[1]), pk2(f1[2], f1[3]) };
    u32x4 ch1 = { pk2(f2[0], f2[1]), pk2(f2[2], f2[3]), pk2(f3[0], f3[1]), pk2(f3[2], f3[3]) };
    const int sw = arow & 7;
    *(u32x4*)((char*)Al + arow * 128 + (((aseg * 2 + 0) ^ sw) * 16)) = ch0;
    *(u32x4*)((char*)Al + arow * 128 + (((aseg * 2 + 1) ^ sw) * 16)) = ch1;
#pragma unroll
    for (int j = 0; j < 2; ++j) {
      const int col = w * 16 + j * 8 + (l >> 3);
      const int c7 = l & 7;
      const ushortT* src = Wt + (size_t)(ct * 64 + col) * 512 + k0 + 8 * (c7 ^ (l >> 3));
      gl16(src, (char*)Bl + (w * 128 + j * 64) * 16);
    }
    __syncthreads();
#pragma unroll
    for (int ks = 0; ks < 2; ++ks) {
      s8v af = *(const s8v*)((char*)Al + (w * 16 + c) * 128 + (((ks * 4 + h) ^ (c & 7)) * 16));
#pragma unroll
      for (int cj = 0; cj < 4; ++cj) {
        s8v bf8 = *(const s8v*)((char*)Bl + (cj * 16 + c) * 128 + (((ks * 4 + h) ^ (c & 7)) * 16));
        acc[cj] = MFMA_BF16(af, bf8, acc[cj]);
      }
    }
    __syncthreads();
  }

  const int colbase = ct * 64;
  const float* bias = (ct == 0) ? bg : (ct == 1) ? bfv : bh;
  const int bo = (ct < 2) ? 0 : (colbase - 128);
  const int rbase = row0 + w * 16 + h * 4;
  if (ct < 2) {
    ushortT* dst = (ct == 0) ? Q : K;
#pragma unroll
    for (int cj = 0; cj < 4; ++cj) {
      const int cl = cj * 16 + c;
      const float bv = bias[cl];
#pragma unroll
      for (int r = 0; r < 4; ++r)
        dst[(size_t)(rbase + r) * 64 + cl] = (ushortT)bfr16(acc[cj][r] + bv);
    }
  } else {
    const int b = row0 >> 12;
    const int n0 = (row0 & 4095) + w * 16 + h * 4;   // multiple of 4, +3 stays in kv-tile
    const int tt = n0 >> 5, kvo = n0 & 31;
#pragma unroll
    for (int cj = 0; cj < 4; ++cj) {
      const int cl = cj * 16 + c;
      const float bv = bias[bo + cl];
      const int vcol = bo + cl;
      u32x2 dd = { pk2(acc[cj][0] + bv, acc[cj][1] + bv),
                   pk2(acc[cj][2] + bv, acc[cj][3] + bv) };
      *(u32x2*)(Vt + (((size_t)(b * 128 + tt) * 512 + vcol) * 32 + kvo)) = dd;
    }
  }
}

// ---------------------------------------------------------------------------
// Kernel 2: flash attention, register-direct K/V (L2-resident), one barrier
// per iteration, P double-buffered in LDS, defer-max rescale.
// grid = 512 (bb = blk&7 -> XCD-local batch), 512 threads (8 waves).
// Waves 0-3 produce P(t+1) (softmax pipelined one tile ahead); all 8 waves
// consume P(t) and accumulate PV over their own 64 V-columns.
// ---------------------------------------------------------------------------
__global__ __launch_bounds__(512) void kattn(const ushortT* __restrict__ Qg,
                                             const ushortT* __restrict__ Kg,
                                             const ushortT* __restrict__ Vt2,
                                             const float* __restrict__ x,
                                             const float* __restrict__ gamma,
                                             float* __restrict__ out) {
  __shared__ __align__(16) uint32_t Pl[2][4 * 64 * 4];   // 8KB frag-major, dbuf
  __shared__ __align__(16) float alpha_s[2][64];
  __shared__ __align__(16) int   flag_s[2][4];
  __shared__ __align__(16) float lsum_s[64];

  const int tid = threadIdx.x;
  const int w = tid >> 6, l = tid & 63, h = l >> 4, c = l & 15;
  const int bb = blockIdx.x & 7, qb = blockIdx.x >> 3;   // XCD-aware swizzle
  const size_t qrow0 = (size_t)bb * 4096 + (size_t)qb * 64;

  f4 acc[4][4];
#pragma unroll
  for (int qi = 0; qi < 4; ++qi)
#pragma unroll
    for (int vj = 0; vj < 4; ++vj) acc[qi][vj] = (f4){0.f, 0.f, 0.f, 0.f};

  const ushortT* Kb = Kg + (size_t)bb * 4096 * 64;
  const ushortT* Vb = Vt2 + (size_t)bb * 512 * 4096;

  // per-lane pointers
  const ushortT* vptr = Vb + (size_t)(w * 64 + c) * 32 + h * 8;  // +16384/iter
  const ushortT* kptr = Kb + (size_t)c * 64 + h * 8;             // +2048/iter

  // Q fragments (B-operand of S^T): q = w*16 + c
  s8v qf[2];
  if (w < 4) {
#pragma unroll
    for (int ks = 0; ks < 2; ++ks)
      qf[ks] = *(const s8v*)(Qg + (qrow0 + w * 16 + c) * 64 + ks * 32 + h * 8);
  }
  float m_run = -__builtin_inff();
  float l_run = 0.0f;

  // softmax producer: consumes preloaded kf regs, writes P/alpha/flag[nb]
  auto produce = [&](const s8v& kf00, const s8v& kf01, const s8v& kf10,
                     const s8v& kf11, int nb) {
    f4 s0 = (f4){0.f, 0.f, 0.f, 0.f}, s1 = (f4){0.f, 0.f, 0.f, 0.f};
    __builtin_amdgcn_s_setprio(1);
    s0 = MFMA_BF16(kf00, qf[0], s0);
    s0 = MFMA_BF16(kf01, qf[1], s0);
    s1 = MFMA_BF16(kf10, qf[0], s1);
    s1 = MFMA_BF16(kf11, qf[1], s1);
    __builtin_amdgcn_s_setprio(0);
    // per-q (lane c) max over kv: 8 in-lane + cross-h
    float tm = fmaxf(fmaxf(fmaxf(s0[0], s0[1]), fmaxf(s0[2], s0[3])),
                     fmaxf(fmaxf(s1[0], s1[1]), fmaxf(s1[2], s1[3])));
    tm = fmaxf(tm, __shfl_xor(tm, 16));
    tm = fmaxf(tm, __shfl_xor(tm, 32));
    const unsigned long long bal = __ballot(tm > m_run + 8.0f);
    float al = 1.0f;
    if (bal) {
      const float mn = fmaxf(m_run, tm);
      al = __expf(m_run - mn);   // 0 on first tile
      m_run = mn;
    }
    float p0 = __expf(s0[0] - m_run), p1 = __expf(s0[1] - m_run);
    float p2 = __expf(s0[2] - m_run), p3 = __expf(s0[3] - m_run);
    float p4 = __expf(s1[0] - m_run), p5 = __expf(s1[1] - m_run);
    float p6 = __expf(s1[2] - m_run), p7 = __expf(s1[3] - m_run);
    float ts = ((p0 + p1) + (p2 + p3)) + ((p4 + p5) + (p6 + p7));
    ts += __shfl_xor(ts, 16);
    ts += __shfl_xor(ts, 32);
    l_run = l_run * al + ts;
    // scatter P -> fragment-major A-layout (verified mapping)
    const int lane0 = (w * 64 + c + 16 * (h >> 1)) * 4 + (h & 1) * 2;
    Pl[nb][lane0 + 0]      = cvtpk(p0, p1);
    Pl[nb][lane0 + 1]      = cvtpk(p2, p3);
    Pl[nb][lane0 + 32 * 4] = cvtpk(p4, p5);   // kj=1: lane' += 32
    Pl[nb][lane0 + 32 * 4 + 1] = cvtpk(p6, p7);
    if (bal && h == 0) alpha_s[nb][w * 16 + c] = al;
    if (l == 0) flag_s[nb][w] = bal ? 1 : 0;
  };

  // ---- prologue: produce P(0) into buffer 0
  if (w < 4) {
    s8v k00 = *(const s8v*)(kptr);
    s8v k01 = *(const s8v*)(kptr + 32);
    s8v k10 = *(const s8v*)(kptr + 1024);
    s8v k11 = *(const s8v*)(kptr + 1024 + 32);
    kptr += 2048;
    produce(k00, k01, k10, k11, 0);
  }
  asm volatile("s_waitcnt lgkmcnt(0)" ::: "memory");
  __builtin_amdgcn_s_barrier();
  asm volatile("" ::: "memory");

  for (int t = 0; t < 128; ++t) {
    const int cur = t & 1;
    // ---- V fragments for tile t (global, L2-hit; oldest in vmcnt queue)
    s8v vfr[4];
    vfr[0] = *(const s8v*)(vptr + 0);
    vfr[1] = *(const s8v*)(vptr + 512);
    vfr[2] = *(const s8v*)(vptr + 1024);
    vfr[3] = *(const s8v*)(vptr + 1536);
    vptr += 16384;
    // ---- K fragments for tile t+1 (stay in flight through PV)
    s8v k00, k01, k10, k11;
    if (w < 4 && t < 127) {
      k00 = *(const s8v*)(kptr);
      k01 = *(const s8v*)(kptr + 32);
      k10 = *(const s8v*)(kptr + 1024);
      k11 = *(const s8v*)(kptr + 1024 + 32);
      kptr += 2048;
    }
    // ---- P fragments + flags for tile t
    i4v fl = *(const i4v*)&flag_s[cur][0];
    s8v pa[4];
#pragma unroll
    for (int qi = 0; qi < 4; ++qi)
      pa[qi] = *(const s8v*)&Pl[cur][(qi * 64 + l) * 4];
    // ---- deferred rescale
#pragma unroll
    for (int qi = 0; qi < 4; ++qi) {
      if (fl[qi]) {
        f4 a4 = *(const f4*)&alpha_s[cur][qi * 16 + h * 4];
#pragma unroll
        for (int vj = 0; vj < 4; ++vj)
#pragma unroll
          for (int r = 0; r < 4; ++r) acc[qi][vj][r] *= a4[r];
      }
    }
    // ---- PV
    __builtin_amdgcn_s_setprio(1);
#pragma unroll
    for (int qi = 0; qi < 4; ++qi)
#pragma unroll
      for (int vj = 0; vj < 4; ++vj)
        acc[qi][vj] = MFMA_BF16(pa[qi], vfr[vj], acc[qi][vj]);
    __builtin_amdgcn_s_setprio(0);
    // ---- produce P(t+1) into the other buffer (kf latency hidden under PV)
    if (t < 127) {
      if (w < 4) produce(k00, k01, k10, k11, cur ^ 1);
      asm volatile("s_waitcnt lgkmcnt(0)" ::: "memory");
      __builtin_amdgcn_s_barrier();
      asm volatile("" ::: "memory");
    }
  }

  // ---- finalize: out = gamma * (acc / l) + x
  if (w < 4 && h == 0) lsum_s[w * 16 + c] = l_run;
  __syncthreads();
#pragma unroll
  for (int qi = 0; qi < 4; ++qi) {
    f4 l4 = *(const f4*)(&lsum_s[qi * 16 + h * 4]);
    f4 rl;
#pragma unroll
    for (int r = 0; r < 4; ++r) rl[r] = 1.0f / l4[r];
#pragma unroll
    for (int vj = 0; vj < 4; ++vj) {
      const int colg = w * 64 + vj * 16 + c;
      const float gm = gamma[colg];
#pragma unroll
      for (int r = 0; r < 4; ++r) {
        const size_t idx = (qrow0 + qi * 16 + h * 4 + r) * 512 + colg;
        out[idx] = gm * (acc[qi][vj][r] * rl[r]) + x[idx];
      }
    }
  }
}

// ---------------------------------------------------------------------------
extern "C" void kernel_launch(void* const* d_in, const int* in_sizes, int n_in,
                              void* d_out, int out_size, void* d_ws, size_t ws_size,
                              hipStream_t stream) {
  const float* x     = (const float*)d_in[0];
  const float* Wg    = (const float*)d_in[1];
  const float* bg    = (const float*)d_in[2];
  const float* Wf    = (const float*)d_in[3];
  const float* bfv   = (const float*)d_in[4];
  const float* Wh    = (const float*)d_in[5];
  const float* bh    = (const float*)d_in[6];
  const float* gamma = (const float*)d_in[7];
  float* out = (float*)d_out;
  char* ws = (char*)d_ws;

  ushortT* Q  = (ushortT*)(ws);
  ushortT* K  = (ushortT*)(ws + ((size_t)4 << 20));
  ushortT* Vt = (ushortT*)(ws + ((size_t)8 << 20));
  ushortT* Wt = (ushortT*)(ws + ((size_t)40 << 20));

  kprep<<<dim3(640), dim3(64), 0, stream>>>(Wg, Wf, Wh, Wt);
  kproj<<<dim3(10, 512), dim3(256), 0, stream>>>(x, Wt, bg, bfv, bh, Q, K, Vt);
  kattn<<<dim3(512), dim3(512), 0, stream>>>(Q, K, Vt, x, gamma, out);
}

// Round 4
// 295.609 us; speedup vs baseline: 1.5542x; 1.5542x over previous
//
#include <hip/hip_runtime.h>
#include <stdint.h>

// ---------- types ----------
using s8v  = __attribute__((ext_vector_type(8))) short;    // 8 bf16 (A/B frag)
using f4   = __attribute__((ext_vector_type(4))) float;    // C/D frag
using u32x4 = __attribute__((ext_vector_type(4))) uint32_t;
using u32x2 = __attribute__((ext_vector_type(2))) uint32_t;
using vf4  = __attribute__((ext_vector_type(4))) float;
using i4v  = __attribute__((ext_vector_type(4))) int;

typedef unsigned short ushortT;

// bf16 round-to-nearest-even
static __device__ __forceinline__ uint32_t bfr16(float f) {
  union { float f; uint32_t u; } v; v.f = f;
  return (v.u + 0x7FFFu + ((v.u >> 16) & 1u)) >> 16;
}
static __device__ __forceinline__ uint32_t pk2(float lo, float hi) {
  return (bfr16(hi) << 16) | (bfr16(lo) & 0xFFFFu);
}
// hardware packed f32x2 -> bf16x2 (RNE)
static __device__ __forceinline__ uint32_t cvtpk(float lo, float hi) {
  uint32_t r;
  asm("v_cvt_pk_bf16_f32 %0, %1, %2" : "=v"(r) : "v"(lo), "v"(hi));
  return r;
}
// async global->LDS, 16B per lane
static __device__ __forceinline__ void gl16(const void* g, void* l) {
  __builtin_amdgcn_global_load_lds((const __attribute__((address_space(1))) uint32_t*)g,
                                   (__attribute__((address_space(3))) uint32_t*)l, 16, 0, 0);
}

#define MFMA_BF16(A, B, C) __builtin_amdgcn_mfma_f32_16x16x32_bf16((A), (B), (C), 0, 0, 0)

// ---------------------------------------------------------------------------
// Kernel 0: weights -> bf16, transposed: Wt[640][512]
// ---------------------------------------------------------------------------
__global__ __launch_bounds__(64) void kprep(const float* __restrict__ Wg,
                                            const float* __restrict__ Wf,
                                            const float* __restrict__ Wh,
                                            ushortT* __restrict__ Wt) {
  const int cIdx = blockIdx.x;     // 0..639
  const int t = threadIdx.x;       // 64
  const float* src; int co, ldc;
  if (cIdx < 64)       { src = Wg; co = cIdx;       ldc = 64;  }
  else if (cIdx < 128) { src = Wf; co = cIdx - 64;  ldc = 64;  }
  else                 { src = Wh; co = cIdx - 128; ldc = 512; }
#pragma unroll
  for (int kk = 0; kk < 8; ++kk) {
    int k = kk * 64 + t;
    Wt[(size_t)cIdx * 512 + k] = (ushortT)bfr16(src[(size_t)k * ldc + co]);
  }
}

// ---------------------------------------------------------------------------
// Kernel 1: projection GEMM.  col-tile 0 -> Q [32768][64]; 1 -> K [32768][64];
// 2..9 -> Vt2 TILED: Vt2[b][kvtile=128][col=512][kv=32].
// ---------------------------------------------------------------------------
__global__ __launch_bounds__(256) void kproj(const float* __restrict__ x,
                                             const ushortT* __restrict__ Wt,
                                             const float* __restrict__ bg,
                                             const float* __restrict__ bfv,
                                             const float* __restrict__ bh,
                                             ushortT* __restrict__ Q,
                                             ushortT* __restrict__ K,
                                             ushortT* __restrict__ Vt) {
  __shared__ ushortT Al[64 * 64];
  __shared__ ushortT Bl[64 * 64];

  const int tid = threadIdx.x;
  const int w = tid >> 6, l = tid & 63, h = l >> 4, c = l & 15;
  const int ct = blockIdx.x, rt = blockIdx.y;
  const int row0 = rt * 64;

  f4 acc[4];
#pragma unroll
  for (int j = 0; j < 4; ++j) acc[j] = (f4){0.f, 0.f, 0.f, 0.f};

  const int arow = tid >> 2, aseg = tid & 3;
  const float* xrow = x + (size_t)(row0 + arow) * 512 + aseg * 16;

  for (int kk = 0; kk < 8; ++kk) {
    const int k0 = kk * 64;
    vf4 f0 = *(const vf4*)(xrow + k0 + 0);
    vf4 f1 = *(const vf4*)(xrow + k0 + 4);
    vf4 f2 = *(const vf4*)(xrow + k0 + 8);
    vf4 f3 = *(const vf4*)(xrow + k0 + 12);
    u32x4 ch0 = { pk2(f0[0], f0[1]), pk2(f0[2], f0[3]), pk2(f1[0], f1[1]), pk2(f1[2], f1[3]) };
    u32x4 ch1 = { pk2(f2[0], f2[1]), pk2(f2[2], f2[3]), pk2(f3[0], f3[1]), pk2(f3[2], f3[3]) };
    const int sw = arow & 7;
    *(u32x4*)((char*)Al + arow * 128 + (((aseg * 2 + 0) ^ sw) * 16)) = ch0;
    *(u32x4*)((char*)Al + arow * 128 + (((aseg * 2 + 1) ^ sw) * 16)) = ch1;
#pragma unroll
    for (int j = 0; j < 2; ++j) {
      const int col = w * 16 + j * 8 + (l >> 3);
      const int c7 = l & 7;
      const ushortT* src = Wt + (size_t)(ct * 64 + col) * 512 + k0 + 8 * (c7 ^ (l >> 3));
      gl16(src, (char*)Bl + (w * 128 + j * 64) * 16);
    }
    __syncthreads();
#pragma unroll
    for (int ks = 0; ks < 2; ++ks) {
      s8v af = *(const s8v*)((char*)Al + (w * 16 + c) * 128 + (((ks * 4 + h) ^ (c & 7)) * 16));
#pragma unroll
      for (int cj = 0; cj < 4; ++cj) {
        s8v bf8 = *(const s8v*)((char*)Bl + (cj * 16 + c) * 128 + (((ks * 4 + h) ^ (c & 7)) * 16));
        acc[cj] = MFMA_BF16(af, bf8, acc[cj]);
      }
    }
    __syncthreads();
  }

  const int colbase = ct * 64;
  const float* bias = (ct == 0) ? bg : (ct == 1) ? bfv : bh;
  const int bo = (ct < 2) ? 0 : (colbase - 128);
  const int rbase = row0 + w * 16 + h * 4;
  if (ct < 2) {
    ushortT* dst = (ct == 0) ? Q : K;
#pragma unroll
    for (int cj = 0; cj < 4; ++cj) {
      const int cl = cj * 16 + c;
      const float bv = bias[cl];
#pragma unroll
      for (int r = 0; r < 4; ++r)
        dst[(size_t)(rbase + r) * 64 + cl] = (ushortT)bfr16(acc[cj][r] + bv);
    }
  } else {
    const int b = row0 >> 12;
    const int n0 = (row0 & 4095) + w * 16 + h * 4;
    const int tt = n0 >> 5, kvo = n0 & 31;
#pragma unroll
    for (int cj = 0; cj < 4; ++cj) {
      const int cl = cj * 16 + c;
      const float bv = bias[bo + cl];
      const int vcol = bo + cl;
      u32x2 dd = { pk2(acc[cj][0] + bv, acc[cj][1] + bv),
                   pk2(acc[cj][2] + bv, acc[cj][3] + bv) };
      *(u32x2*)(Vt + (((size_t)(b * 128 + tt) * 512 + vcol) * 32 + kvo)) = dd;
    }
  }
}

// ---------------------------------------------------------------------------
// Kernel 2: flash attention.  Register-direct V (split 2+2), K via tiny LDS
// dbuf (gl16, staged 2 tiles ahead), P double-buffered in LDS, defer-max.
// __launch_bounds__(512,4): target 2 blocks/CU (16 waves) — arch VGPR <= 64.
// ---------------------------------------------------------------------------
__global__ __launch_bounds__(512, 4) void kattn(const ushortT* __restrict__ Qg,
                                                const ushortT* __restrict__ Kg,
                                                const ushortT* __restrict__ Vt2,
                                                const float* __restrict__ x,
                                                const float* __restrict__ gamma,
                                                float* __restrict__ out) {
  __shared__ __align__(16) uint32_t Pl[2][4 * 64 * 4];   // 8KB frag-major, dbuf
  __shared__ __align__(16) ushortT Klds[2][32 * 64];     // 8KB K tiles, dbuf
  __shared__ __align__(16) float alpha_s[2][64];
  __shared__ __align__(16) int   flag_s[2][4];
  __shared__ __align__(16) float lsum_s[64];

  const int tid = threadIdx.x;
  const int w = tid >> 6, l = tid & 63, h = l >> 4, c = l & 15;
  const int bb = blockIdx.x & 7, qb = blockIdx.x >> 3;   // XCD-aware swizzle
  const size_t qrow0 = (size_t)bb * 4096 + (size_t)qb * 64;

  f4 acc[4][4];
#pragma unroll
  for (int qi = 0; qi < 4; ++qi)
#pragma unroll
    for (int vj = 0; vj < 4; ++vj) acc[qi][vj] = (f4){0.f, 0.f, 0.f, 0.f};

  const ushortT* Kb = Kg + (size_t)bb * 4096 * 64;
  const ushortT* Vb = Vt2 + (size_t)bb * 512 * 4096;

  // per-lane pointers
  const ushortT* vptr = Vb + (size_t)(w * 64 + c) * 32 + h * 8;  // +16384/iter
  // gl16 K staging source (pre-swizzled), starts at tile 1
  const ushortT* kap = Kb + 2048 + (size_t)(w * 8 + (l >> 3)) * 64 +
                       8 * ((l & 7) ^ (l >> 3));

  // Q fragments (B-operand of S^T): q = w*16 + c
  s8v qf[2];
  if (w < 4) {
#pragma unroll
    for (int ks = 0; ks < 2; ++ks)
      qf[ks] = *(const s8v*)(Qg + (qrow0 + w * 16 + c) * 64 + ks * 32 + h * 8);
  }
  float m_run = -__builtin_inff();
  float l_run = 0.0f;

  // softmax producer: consumes k-frag regs, writes P/alpha/flag[nb]
  auto produce = [&](const s8v& kf00, const s8v& kf01, const s8v& kf10,
                     const s8v& kf11, int nb) {
    f4 s0 = (f4){0.f, 0.f, 0.f, 0.f}, s1 = (f4){0.f, 0.f, 0.f, 0.f};
    __builtin_amdgcn_s_setprio(1);
    s0 = MFMA_BF16(kf00, qf[0], s0);
    s0 = MFMA_BF16(kf01, qf[1], s0);
    s1 = MFMA_BF16(kf10, qf[0], s1);
    s1 = MFMA_BF16(kf11, qf[1], s1);
    __builtin_amdgcn_s_setprio(0);
    float tm = fmaxf(fmaxf(fmaxf(s0[0], s0[1]), fmaxf(s0[2], s0[3])),
                     fmaxf(fmaxf(s1[0], s1[1]), fmaxf(s1[2], s1[3])));
    tm = fmaxf(tm, __shfl_xor(tm, 16));
    tm = fmaxf(tm, __shfl_xor(tm, 32));
    const unsigned long long bal = __ballot(tm > m_run + 8.0f);
    float al = 1.0f;
    if (bal) {
      const float mn = fmaxf(m_run, tm);
      al = __expf(m_run - mn);   // 0 on first tile
      m_run = mn;
    }
    float p0 = __expf(s0[0] - m_run), p1 = __expf(s0[1] - m_run);
    float p2 = __expf(s0[2] - m_run), p3 = __expf(s0[3] - m_run);
    float p4 = __expf(s1[0] - m_run), p5 = __expf(s1[1] - m_run);
    float p6 = __expf(s1[2] - m_run), p7 = __expf(s1[3] - m_run);
    float ts = ((p0 + p1) + (p2 + p3)) + ((p4 + p5) + (p6 + p7));
    ts += __shfl_xor(ts, 16);
    ts += __shfl_xor(ts, 32);
    l_run = l_run * al + ts;
    const int lane0 = (w * 64 + c + 16 * (h >> 1)) * 4 + (h & 1) * 2;
    Pl[nb][lane0 + 0]          = cvtpk(p0, p1);
    Pl[nb][lane0 + 1]          = cvtpk(p2, p3);
    Pl[nb][lane0 + 32 * 4]     = cvtpk(p4, p5);   // kj=1: lane' += 32
    Pl[nb][lane0 + 32 * 4 + 1] = cvtpk(p6, p7);
    if (bal && h == 0) alpha_s[nb][w * 16 + c] = al;
    if (l == 0) flag_s[nb][w] = bal ? 1 : 0;
  };

  // ---- prologue: produce P(0) (direct global K), stage K(1) -> Klds[1]
  if (w < 4) {
    const ushortT* kd = Kb + (size_t)c * 64 + h * 8;
    s8v k00 = *(const s8v*)(kd);
    s8v k01 = *(const s8v*)(kd + 32);
    s8v k10 = *(const s8v*)(kd + 1024);
    s8v k11 = *(const s8v*)(kd + 1024 + 32);
    produce(k00, k01, k10, k11, 0);
    gl16(kap, (char*)Klds[1] + w * 1024);
    kap += 2048;   // -> tile 2
  }
  asm volatile("s_waitcnt vmcnt(0) lgkmcnt(0)" ::: "memory");
  __builtin_amdgcn_s_barrier();

  for (int t = 0; t < 128; ++t) {
    const int cur = t & 1;
    // ---- V fragments half A for tile t
    s8v vfA0 = *(const s8v*)(vptr + 0);
    s8v vfA1 = *(const s8v*)(vptr + 512);
    // ---- stage K(t+2) -> Klds[t&1] (read next iter; write/read barrier-sep)
    if (w < 4 && t < 126) {
      gl16(kap, (char*)Klds[cur] + w * 1024);
      kap += 2048;
    }
    // ---- P fragments + flags for tile t
    i4v fl = *(const i4v*)&flag_s[cur][0];
    s8v pa[4];
#pragma unroll
    for (int qi = 0; qi < 4; ++qi)
      pa[qi] = *(const s8v*)&Pl[cur][(qi * 64 + l) * 4];
    // ---- deferred rescale
#pragma unroll
    for (int qi = 0; qi < 4; ++qi) {
      if (fl[qi]) {
        f4 a4 = *(const f4*)&alpha_s[cur][qi * 16 + h * 4];
#pragma unroll
        for (int vj = 0; vj < 4; ++vj)
#pragma unroll
          for (int r = 0; r < 4; ++r) acc[qi][vj][r] *= a4[r];
      }
    }
    // ---- PV half A
    __builtin_amdgcn_s_setprio(1);
#pragma unroll
    for (int qi = 0; qi < 4; ++qi) {
      acc[qi][0] = MFMA_BF16(pa[qi], vfA0, acc[qi][0]);
      acc[qi][1] = MFMA_BF16(pa[qi], vfA1, acc[qi][1]);
    }
    __builtin_amdgcn_s_setprio(0);
    // ---- V fragments half B (latency covered by co-resident block)
    s8v vfB0 = *(const s8v*)(vptr + 1024);
    s8v vfB1 = *(const s8v*)(vptr + 1536);
    vptr += 16384;
    __builtin_amdgcn_s_setprio(1);
#pragma unroll
    for (int qi = 0; qi < 4; ++qi) {
      acc[qi][2] = MFMA_BF16(pa[qi], vfB0, acc[qi][2]);
      acc[qi][3] = MFMA_BF16(pa[qi], vfB1, acc[qi][3]);
    }
    __builtin_amdgcn_s_setprio(0);
    // ---- produce P(t+1) from Klds[(t+1)&1]
    if (t < 127) {
      if (w < 4) {
        const char* kb2 = (const char*)Klds[cur ^ 1];
        s8v k00 = *(const s8v*)(kb2 + (size_t)c * 128 + (((0 + h) ^ (c & 7)) * 16));
        s8v k01 = *(const s8v*)(kb2 + (size_t)c * 128 + (((4 + h) ^ (c & 7)) * 16));
        s8v k10 = *(const s8v*)(kb2 + (size_t)(16 + c) * 128 + (((0 + h) ^ (c & 7)) * 16));
        s8v k11 = *(const s8v*)(kb2 + (size_t)(16 + c) * 128 + (((4 + h) ^ (c & 7)) * 16));
        produce(k00, k01, k10, k11, cur ^ 1);
      }
      // drain: own gl16 (K t+2) must be complete before others read it next
      // iter; lgkm: P writes visible.
      asm volatile("s_waitcnt vmcnt(0) lgkmcnt(0)" ::: "memory");
      __builtin_amdgcn_s_barrier();
    }
  }

  // ---- finalize: out = gamma * (acc / l) + x
  if (w < 4 && h == 0) lsum_s[w * 16 + c] = l_run;
  __syncthreads();
#pragma unroll
  for (int qi = 0; qi < 4; ++qi) {
    f4 l4 = *(const f4*)(&lsum_s[qi * 16 + h * 4]);
    f4 rl;
#pragma unroll
    for (int r = 0; r < 4; ++r) rl[r] = 1.0f / l4[r];
#pragma unroll
    for (int vj = 0; vj < 4; ++vj) {
      const int colg = w * 64 + vj * 16 + c;
      const float gm = gamma[colg];
#pragma unroll
      for (int r = 0; r < 4; ++r) {
        const size_t idx = (qrow0 + qi * 16 + h * 4 + r) * 512 + colg;
        out[idx] = gm * (acc[qi][vj][r] * rl[r]) + x[idx];
      }
    }
  }
}

// ---------------------------------------------------------------------------
extern "C" void kernel_launch(void* const* d_in, const int* in_sizes, int n_in,
                              void* d_out, int out_size, void* d_ws, size_t ws_size,
                              hipStream_t stream) {
  const float* x     = (const float*)d_in[0];
  const float* Wg    = (const float*)d_in[1];
  const float* bg    = (const float*)d_in[2];
  const float* Wf    = (const float*)d_in[3];
  const float* bfv   = (const float*)d_in[4];
  const float* Wh    = (const float*)d_in[5];
  const float* bh    = (const float*)d_in[6];
  const float* gamma = (const float*)d_in[7];
  float* out = (float*)d_out;
  char* ws = (char*)d_ws;

  ushortT* Q  = (ushortT*)(ws);
  ushortT* K  = (ushortT*)(ws + ((size_t)4 << 20));
  ushortT* Vt = (ushortT*)(ws + ((size_t)8 << 20));
  ushortT* Wt = (ushortT*)(ws + ((size_t)40 << 20));

  kprep<<<dim3(640), dim3(64), 0, stream>>>(Wg, Wf, Wh, Wt);
  kproj<<<dim3(10, 512), dim3(256), 0, stream>>>(x, Wt, bg, bfv, bh, Q, K, Vt);
  kattn<<<dim3(512), dim3(512), 0, stream>>>(Q, K, Vt, x, gamma, out);
}